// Round 13
// baseline (154.385 us; speedup 1.0000x reference)
//
#include <hip/hip_runtime.h>
#include <stdint.h>

#define B_  16
#define C_  512
#define S_  1024
#define NH  4
#define HD  128
#define BS  (B_*S_)

typedef __attribute__((ext_vector_type(8))) short   short8;
typedef __attribute__((ext_vector_type(4))) float   f32x4;
typedef __attribute__((ext_vector_type(4))) unsigned int uint4v;

__device__ __forceinline__ unsigned short f2bf(float f) {
    unsigned u = __float_as_uint(f);
    unsigned r = (u + 0x7fffu + ((u >> 16) & 1u)) >> 16;
    return (unsigned short)r;
}

__device__ __forceinline__ unsigned cvt_pk_bf16(float a, float b) {
    unsigned r;
    asm("v_cvt_pk_bf16_f32 %0, %1, %2" : "=v"(r) : "v"(a), "v"(b));
    return r;
}

// ---------------------------------------------------------------- GroupNorm
__global__ void gn_partial(const float* __restrict__ x, float* __restrict__ part) {
    int b = blockIdx.x, chunk = blockIdx.y;           // 16 x 32
    const float4* xb = (const float4*)(x + (size_t)b * C_ * S_);
    int base = chunk * 4096 + threadIdx.x;
    float s = 0.f, ss = 0.f;
#pragma unroll
    for (int i = 0; i < 16; ++i) {
        float4 v = xb[base + i * 256];
        s  += v.x + v.y + v.z + v.w;
        ss += v.x*v.x + v.y*v.y + v.z*v.z + v.w*v.w;
    }
    for (int off = 32; off; off >>= 1) { s += __shfl_down(s, off); ss += __shfl_down(ss, off); }
    __shared__ float red[2][4];
    int wv = threadIdx.x >> 6;
    if ((threadIdx.x & 63) == 0) { red[0][wv] = s; red[1][wv] = ss; }
    __syncthreads();
    if (threadIdx.x == 0) {
        s  = red[0][0] + red[0][1] + red[0][2] + red[0][3];
        ss = red[1][0] + red[1][1] + red[1][2] + red[1][3];
        part[(b*32 + chunk)*2 + 0] = s;
        part[(b*32 + chunk)*2 + 1] = ss;
    }
}

// apply GN + transpose (B,C,S) -> (B,S,C) bf16
__global__ void gn_apply_t(const float* __restrict__ x, const float* __restrict__ part,
                           const float* __restrict__ gw, const float* __restrict__ gb,
                           unsigned short* __restrict__ seq) {
    int st = blockIdx.x, ct = blockIdx.y, b = blockIdx.z;   // 16, 8, 16
    float s1 = 0.f, s2 = 0.f;
#pragma unroll
    for (int i = 0; i < 32; ++i) { s1 += part[(b*32+i)*2]; s2 += part[(b*32+i)*2+1]; }
    const float invN = 1.0f / (float)(C_ * S_);
    float mean = s1 * invN;
    float var  = s2 * invN - mean * mean;
    float rstd = rsqrtf(var + 1e-5f);

    __shared__ unsigned short tile[64][72];
    int c0 = ct * 64, s0 = st * 64;
    const float* xb = x + ((size_t)b * C_ + c0) * S_ + s0;
    int tr = threadIdx.x >> 4, tj = (threadIdx.x & 15) * 4;
#pragma unroll
    for (int p = 0; p < 4; ++p) {
        int i = tr + p * 16;
        float w  = gw[c0 + i];
        float bb = gb[c0 + i];
        float4 v = *(const float4*)(xb + (size_t)i * S_ + tj);
        tile[i][tj+0] = f2bf((v.x - mean) * rstd * w + bb);
        tile[i][tj+1] = f2bf((v.y - mean) * rstd * w + bb);
        tile[i][tj+2] = f2bf((v.z - mean) * rstd * w + bb);
        tile[i][tj+3] = f2bf((v.w - mean) * rstd * w + bb);
    }
    __syncthreads();
    int j  = threadIdx.x >> 2;
    int cc = (threadIdx.x & 3) * 16;
    unsigned short tmp[16] __attribute__((aligned(16)));
#pragma unroll
    for (int i = 0; i < 16; ++i) tmp[i] = tile[cc + i][j];
    unsigned short* dst = seq + ((size_t)(b * S_ + s0 + j)) * C_ + c0 + cc;
    *(uint4v*)dst       = *(uint4v*)tmp;
    *(uint4v*)(dst + 8) = *(uint4v*)(tmp + 8);
}

// ---------------------------------------------------------------- weights cast
__global__ void cvt_w(const float* __restrict__ wq, const float* __restrict__ wk,
                      const float* __restrict__ wv, const float* __restrict__ wo,
                      unsigned short* __restrict__ wqkv, unsigned short* __restrict__ wobf) {
    int m = blockIdx.y;
    const float* src = (m == 0) ? wq : (m == 1) ? wk : (m == 2) ? wv : wo;
    unsigned short* dst = (m < 3) ? (wqkv + (size_t)m * C_ * C_) : wobf;
    int i = blockIdx.x * 256 + threadIdx.x;                 // 65536 float4 per matrix
    float4 v = ((const float4*)src)[i];
    unsigned short o[4] __attribute__((aligned(8)));
    o[0] = f2bf(v.x); o[1] = f2bf(v.y); o[2] = f2bf(v.z); o[3] = f2bf(v.w);
    *(unsigned long long*)(dst + (size_t)i * 4) = *(unsigned long long*)o;
}

// ---------------------------------------------------------------- 128x128 GEMM core
// C[m][n] = sum_k A[m][k]*B[n][k]; A,B row-major bf16 with row stride K.
__device__ __forceinline__ void gemm128_bt(const unsigned short* __restrict__ Ab,
                                           const unsigned short* __restrict__ Bb,
                                           const int K,
                                           unsigned short* lA, unsigned short* lB,
                                           f32x4 acc[4][4]) {
    const int t = threadIdx.x;
    const int w = t >> 6, l = t & 63;
    const int wr = (w >> 1) * 64, wc = (w & 1) * 64;
    const int lrow = l & 15;
    const int lk8  = (l >> 4) * 8;
#pragma unroll
    for (int mi = 0; mi < 4; ++mi)
#pragma unroll
        for (int ni = 0; ni < 4; ++ni)
            acc[mi][ni] = (f32x4){0.f, 0.f, 0.f, 0.f};

    for (int kt = 0; kt < K; kt += 64) {
#pragma unroll
        for (int j = 0; j < 4; ++j) {
            const int lin = j * 256 + t;
            const int row = lin >> 3, ch = lin & 7;
            __builtin_amdgcn_global_load_lds(
                (const __attribute__((address_space(1))) unsigned int*)(Ab + (size_t)row * K + kt + ch * 8),
                (__attribute__((address_space(3))) unsigned int*)(lA + (size_t)(j * 256 + w * 64) * 8),
                16, 0, 0);
        }
#pragma unroll
        for (int j = 0; j < 4; ++j) {
            const int lin = j * 256 + t;
            const int row = lin >> 3, ch = lin & 7;
            __builtin_amdgcn_global_load_lds(
                (const __attribute__((address_space(1))) unsigned int*)(Bb + (size_t)row * K + kt + ch * 8),
                (__attribute__((address_space(3))) unsigned int*)(lB + (size_t)(j * 256 + w * 64) * 8),
                16, 0, 0);
        }
        __syncthreads();
#pragma unroll
        for (int kk = 0; kk < 2; ++kk) {
            short8 af[4], bf[4];
            const int ko = lk8 + kk * 32;
#pragma unroll
            for (int mi = 0; mi < 4; ++mi)
                af[mi] = *(const short8*)&lA[(size_t)(wr + mi * 16 + lrow) * 64 + ko];
#pragma unroll
            for (int ni = 0; ni < 4; ++ni)
                bf[ni] = *(const short8*)&lB[(size_t)(wc + ni * 16 + lrow) * 64 + ko];
#pragma unroll
            for (int mi = 0; mi < 4; ++mi)
#pragma unroll
                for (int ni = 0; ni < 4; ++ni)
                    acc[mi][ni] = __builtin_amdgcn_mfma_f32_16x16x32_bf16(af[mi], bf[ni], acc[mi][ni], 0, 0, 0);
        }
        __syncthreads();
    }
}

// ---------------------------------------------------------------- QKV GEMM (+fused V transpose)
// Q/K epilogue: stage (s,d) tile in LDS, then fully-coalesced b128 stores.
__global__ __launch_bounds__(256) void qkv_gemm(
        const unsigned short* __restrict__ seq, const unsigned short* __restrict__ wqkv,
        const float* __restrict__ bq, const float* __restrict__ bk, const float* __restrict__ bv,
        unsigned short* __restrict__ qb, unsigned short* __restrict__ kb, unsigned short* __restrict__ vtb) {
    __shared__ unsigned short sbuf[128 * 136];              // gemm: first 16384; epilogue: all
    unsigned short* lA = sbuf;
    unsigned short* lB = sbuf + 128 * 64;
    int mb = blockIdx.x, nb = blockIdx.y;                   // 128, 12
    f32x4 acc[4][4];
    gemm128_bt(seq + (size_t)mb * 128 * C_, wqkv + (size_t)nb * 128 * C_, C_, lA, lB, acc);

    int mat = nb >> 2;                                      // 0=q 1=k 2=v
    int w = threadIdx.x >> 6, l = threadIdx.x & 63;
    int l15 = l & 15, g = l >> 4;
    int wr = (w >> 1) * 64, wc = (w & 1) * 64;
    int b  = mb >> 3;
    int s0 = (mb & 7) * 128;
    int h  = nb & 3;

    if (mat < 2) {
        const float* bias = (mat == 0) ? bq : bk;
        unsigned short* out = (mat == 0) ? qb : kb;
        // q scale: 1/sqrt(128) * log2(e)  (attention computed in exp2 domain)
        float oscale = (mat == 0) ? 0.12751879523087253f : 1.0f;
#pragma unroll
        for (int mi = 0; mi < 4; ++mi)
#pragma unroll
            for (int ni = 0; ni < 4; ++ni) {
                int dloc = wc + ni * 16 + l15;               // d
                int sloc = wr + mi * 16 + g * 4;             // s (rows sloc..sloc+3)
                float bia = bias[h * 128 + dloc];
#pragma unroll
                for (int r = 0; r < 4; ++r)
                    sbuf[(sloc + r) * 136 + dloc] = f2bf((acc[mi][ni][r] + bia) * oscale);
            }
        __syncthreads();
        unsigned short* dst = out + ((size_t)(b * NH + h) * S_ + s0) * HD;
#pragma unroll
        for (int p = 0; p < 4; ++p) {
            int idx = p * 256 + threadIdx.x;                 // 1024 chunks of 16B
            int srow = idx >> 3, cc = (idx & 7) * 8;
            short8 vv = *(const short8*)&sbuf[srow * 136 + cc];
            *(short8*)(dst + (size_t)idx * 8) = vv;
        }
    } else {
        // V: bias, then transpose through LDS -> vt (b,h,d,s)
#pragma unroll
        for (int mi = 0; mi < 4; ++mi)
#pragma unroll
            for (int ni = 0; ni < 4; ++ni) {
                int dloc = wc + ni * 16 + l15;
                int mloc = wr + mi * 16 + g * 4;
                float bia = bv[h * 128 + dloc];
#pragma unroll
                for (int r = 0; r < 4; ++r)
                    sbuf[dloc * 136 + mloc + r] = f2bf(acc[mi][ni][r] + bia);
            }
        __syncthreads();
        unsigned short* dst = vtb + ((size_t)(b * NH + h)) * HD * S_ + s0;
#pragma unroll
        for (int p = 0; p < 8; ++p) {
            int idx = p * 256 + threadIdx.x;
            int d = idx >> 4, cc = (idx & 15) * 8;
            short8 vv = *(const short8*)&sbuf[d * 136 + cc];
            *(short8*)(dst + (size_t)d * S_ + cc) = vv;
        }
    }
}

// ---------------------------------------------------------------- flash attention
// q,k: (bh, s, d) bf16 (q pre-scaled by 1/sqrt(d)*log2e); vt: (bh, d, s) bf16; o: (b, s, c) bf16
// Swapped QK^T (mfma(K,Q) = S^T); lane (g=l>>4, l15=l&15) owns q-row l15 (half a)
// and l15+16 (half b). 4 waves x 32 q = 128 q/block. KVBLK=32, K/V double-buffered,
// issue-early prefetch, one barrier/tile. LDS 40KB -> 4 blocks/CU; NO reg cap, NO setprio
// (R4's regression was the __launch_bounds__(256,4) spill, not KVBLK=32 itself).
__global__ __launch_bounds__(256) void flash_attn(
        const unsigned short* __restrict__ q, const unsigned short* __restrict__ k,
        const unsigned short* __restrict__ vt, unsigned short* __restrict__ o) {
    int bh = blockIdx.x, qblk = blockIdx.y;                 // 64, 8
    int t = threadIdx.x, w = t >> 6, l = t & 63;
    int l15 = l & 15, g = l >> 4;
    int sw = l15 & 7;                                       // 3-bit XOR mask on 8B chunks
    __shared__ unsigned short lK[2][32 * 128];              // [kv][d], swizzled 16B chunks
    __shared__ unsigned short lV[2][128 * 32];              // [d][kv], swizzled 16B chunks
    __shared__ unsigned short lP[4][32 * 32];               // per-wave P [32 q][32 kv], 8B chunks

    const size_t bh_base = (size_t)bh * S_ * HD;
    int q0 = qblk * 128 + w * 32;

    // Q fragments (B operand) for both q-halves
    short8 qa[4], qb_[4];
    const unsigned short* qp = q + bh_base + (size_t)(q0 + l15) * HD + g * 8;
#pragma unroll
    for (int kc = 0; kc < 4; ++kc) {
        qa[kc]  = *(const short8*)(qp + kc * 32);
        qb_[kc] = *(const short8*)(qp + 16 * HD + kc * 32);
    }

    f32x4 oa[8], ob[8];
#pragma unroll
    for (int i = 0; i < 8; ++i) { oa[i] = (f32x4){0.f,0.f,0.f,0.f}; ob[i] = (f32x4){0.f,0.f,0.f,0.f}; }
    float m_a = -1e30f, l_a = 0.f, m_b = -1e30f, l_b = 0.f;
    unsigned short* myP = &lP[w][0];

#define STAGE_TILE(buf, kv0_) do {                                                     \
    int kv0s = (kv0_);                                                                 \
    _Pragma("unroll")                                                                  \
    for (int j = 0; j < 2; ++j) {                                                      \
        int lin = j * 256 + t;                                                         \
        int row = lin >> 4, c16 = lin & 15;                                            \
        int sc  = (c16 & 8) | ((c16 ^ row) & 7);                                       \
        __builtin_amdgcn_global_load_lds(                                              \
            (const __attribute__((address_space(1))) unsigned int*)(k + bh_base + (size_t)(kv0s + row) * HD + sc * 8), \
            (__attribute__((address_space(3))) unsigned int*)(&lK[buf][0] + (size_t)(j * 256 + w * 64) * 8), \
            16, 0, 0);                                                                 \
    }                                                                                  \
    _Pragma("unroll")                                                                  \
    for (int j = 0; j < 2; ++j) {                                                      \
        int lin = j * 256 + t;                                                         \
        int row = lin >> 2, c4 = lin & 3;                                              \
        int sc  = (c4 ^ row) & 3;                                                      \
        __builtin_amdgcn_global_load_lds(                                              \
            (const __attribute__((address_space(1))) unsigned int*)(vt + bh_base + (size_t)row * S_ + kv0s + sc * 8), \
            (__attribute__((address_space(3))) unsigned int*)(&lV[buf][0] + (size_t)(j * 256 + w * 64) * 8), \
            16, 0, 0);                                                                 \
    }                                                                                  \
} while (0)

    STAGE_TILE(0, 0);
    __syncthreads();
    int cur = 0;

    for (int kt = 0; kt < 32; ++kt) {
        if (kt < 31) STAGE_TILE(cur ^ 1, (kt + 1) * 32);    // prefetch overlaps compute
        const unsigned short* lKc = &lK[cur][0];
        const unsigned short* lVc = &lV[cur][0];

        // S^T = K @ Q^T for both q-halves (K frag read once, used twice)
        f32x4 sa[2], sb[2];
#pragma unroll
        for (int nb = 0; nb < 2; ++nb) {
            sa[nb] = (f32x4){0.f,0.f,0.f,0.f};
            sb[nb] = (f32x4){0.f,0.f,0.f,0.f};
        }
#pragma unroll
        for (int kc = 0; kc < 4; ++kc)
#pragma unroll
            for (int nb = 0; nb < 2; ++nb) {
                int row = nb * 16 + l15;
                int gg  = g + kc * 4;
                int ch  = (gg & 8) | ((gg ^ row) & 7);
                short8 kf = *(const short8*)&lKc[(size_t)row * 128 + ch * 8];
                sa[nb] = __builtin_amdgcn_mfma_f32_16x16x32_bf16(kf, qa[kc],  sa[nb], 0, 0, 0);
                sb[nb] = __builtin_amdgcn_mfma_f32_16x16x32_bf16(kf, qb_[kc], sb[nb], 0, 0, 0);
            }

        // row max per half (q = l15 / l15+16): 8 values each + 2 shuffles
        float mxa = fmaxf(fmaxf(sa[0][0], sa[0][1]), fmaxf(sa[0][2], sa[0][3]));
        float mxb = fmaxf(fmaxf(sb[0][0], sb[0][1]), fmaxf(sb[0][2], sb[0][3]));
        mxa = fmaxf(mxa, fmaxf(fmaxf(sa[1][0], sa[1][1]), fmaxf(sa[1][2], sa[1][3])));
        mxb = fmaxf(mxb, fmaxf(fmaxf(sb[1][0], sb[1][1]), fmaxf(sb[1][2], sb[1][3])));
        mxa = fmaxf(mxa, __shfl_xor(mxa, 16)); mxa = fmaxf(mxa, __shfl_xor(mxa, 32));
        mxb = fmaxf(mxb, __shfl_xor(mxb, 16)); mxb = fmaxf(mxb, __shfl_xor(mxb, 32));

        // defer-max: rescale only when a row grew by > 8 (log2 units)
        if (!__all((mxa - m_a <= 8.f) && (mxb - m_b <= 8.f))) {
            float mna = fmaxf(m_a, mxa), mnb = fmaxf(m_b, mxb);
            float ala = exp2f(m_a - mna), alb = exp2f(m_b - mnb);
            m_a = mna; m_b = mnb; l_a *= ala; l_b *= alb;
            float a0 = __shfl(ala, g*4+0), a1 = __shfl(ala, g*4+1),
                  a2 = __shfl(ala, g*4+2), a3 = __shfl(ala, g*4+3);
            float b0 = __shfl(alb, g*4+0), b1 = __shfl(alb, g*4+1),
                  b2 = __shfl(alb, g*4+2), b3 = __shfl(alb, g*4+3);
#pragma unroll
            for (int dn = 0; dn < 8; ++dn) {
                oa[dn][0] *= a0; oa[dn][1] *= a1; oa[dn][2] *= a2; oa[dn][3] *= a3;
                ob[dn][0] *= b0; ob[dn][1] *= b1; ob[dn][2] *= b2; ob[dn][3] *= b3;
            }
        }

        // P = exp2(S - m); pack 4 kv -> one b64 store per (nb, half)
        float psa = 0.f, psb = 0.f;
#pragma unroll
        for (int nb = 0; nb < 2; ++nb) {
            float p0 = exp2f(sa[nb][0] - m_a), p1 = exp2f(sa[nb][1] - m_a);
            float p2 = exp2f(sa[nb][2] - m_a), p3 = exp2f(sa[nb][3] - m_a);
            psa += (p0 + p1) + (p2 + p3);
            unsigned d0 = cvt_pk_bf16(p0, p1), d1 = cvt_pk_bf16(p2, p3);
            int c = (nb * 4 + g) ^ sw;
            *(unsigned long long*)(myP + l15 * 32 + c * 4) =
                (unsigned long long)d0 | ((unsigned long long)d1 << 32);
            float r0 = exp2f(sb[nb][0] - m_b), r1 = exp2f(sb[nb][1] - m_b);
            float r2 = exp2f(sb[nb][2] - m_b), r3 = exp2f(sb[nb][3] - m_b);
            psb += (r0 + r1) + (r2 + r3);
            unsigned e0 = cvt_pk_bf16(r0, r1), e1 = cvt_pk_bf16(r2, r3);
            *(unsigned long long*)(myP + (l15 + 16) * 32 + c * 4) =
                (unsigned long long)e0 | ((unsigned long long)e1 << 32);
        }
        psa += __shfl_xor(psa, 16); psa += __shfl_xor(psa, 32);
        psb += __shfl_xor(psb, 16); psb += __shfl_xor(psb, 32);
        l_a += psa; l_b += psb;

        // O += P @ V  (single K=32 step; V frag read once, both halves)
        union { unsigned long long u[2]; short8 v; } pa, pb;
        pa.u[0] = *(const unsigned long long*)(myP + l15 * 32 + (((2*g)     ^ sw) * 4));
        pa.u[1] = *(const unsigned long long*)(myP + l15 * 32 + (((2*g + 1) ^ sw) * 4));
        pb.u[0] = *(const unsigned long long*)(myP + (l15 + 16) * 32 + (((2*g)     ^ sw) * 4));
        pb.u[1] = *(const unsigned long long*)(myP + (l15 + 16) * 32 + (((2*g + 1) ^ sw) * 4));
#pragma unroll
        for (int dn = 0; dn < 8; ++dn) {
            int vrow = dn * 16 + l15;
            int vch  = (g ^ vrow) & 3;
            short8 vf = *(const short8*)&lVc[(size_t)vrow * 32 + vch * 8];
            oa[dn] = __builtin_amdgcn_mfma_f32_16x16x32_bf16(pa.v, vf, oa[dn], 0, 0, 0);
            ob[dn] = __builtin_amdgcn_mfma_f32_16x16x32_bf16(pb.v, vf, ob[dn], 0, 0, 0);
        }
        __syncthreads();                                    // prefetch landed; buffers swappable
        cur ^= 1;
    }
#undef STAGE_TILE

    float ia = 1.0f / l_a, ib = 1.0f / l_b;
    float ia0 = __shfl(ia, g*4+0), ia1 = __shfl(ia, g*4+1),
          ia2 = __shfl(ia, g*4+2), ia3 = __shfl(ia, g*4+3);
    float ib0 = __shfl(ib, g*4+0), ib1 = __shfl(ib, g*4+1),
          ib2 = __shfl(ib, g*4+2), ib3 = __shfl(ib, g*4+3);
    int b = bh >> 2, h = bh & 3;
    int sra = q0 + g * 4;
#pragma unroll
    for (int dn = 0; dn < 8; ++dn) {
        int cbase = h * HD + dn * 16 + l15;
        o[((size_t)(b * S_ + sra + 0)) * C_ + cbase]  = f2bf(oa[dn][0] * ia0);
        o[((size_t)(b * S_ + sra + 1)) * C_ + cbase]  = f2bf(oa[dn][1] * ia1);
        o[((size_t)(b * S_ + sra + 2)) * C_ + cbase]  = f2bf(oa[dn][2] * ia2);
        o[((size_t)(b * S_ + sra + 3)) * C_ + cbase]  = f2bf(oa[dn][3] * ia3);
        o[((size_t)(b * S_ + sra + 16)) * C_ + cbase] = f2bf(ob[dn][0] * ib0);
        o[((size_t)(b * S_ + sra + 17)) * C_ + cbase] = f2bf(ob[dn][1] * ib1);
        o[((size_t)(b * S_ + sra + 18)) * C_ + cbase] = f2bf(ob[dn][2] * ib2);
        o[((size_t)(b * S_ + sra + 19)) * C_ + cbase] = f2bf(ob[dn][3] * ib3);
    }
}

// ---------------------------------------------------------------- out-proj (+bias+residual)
// computes out[b][c][s] = sum_k wo[c][k]*attn[b][s][k] + bo[c] + x[b][c][s]
__global__ __launch_bounds__(256) void oproj_gemm(
        const unsigned short* __restrict__ wobf, const unsigned short* __restrict__ attn,
        const float* __restrict__ bo, const float* __restrict__ x, float* __restrict__ out) {
    int cbk = blockIdx.x, sb = blockIdx.y, b = blockIdx.z;  // 4, 8, 16
    __shared__ unsigned short lA[128 * 64], lB[128 * 64];
    f32x4 acc[4][4];
    gemm128_bt(wobf + (size_t)cbk * 128 * C_,
               attn + ((size_t)b * S_ + sb * 128) * C_, C_, lA, lB, acc);

    int w = threadIdx.x >> 6, l = threadIdx.x & 63;
    int wr = (w >> 1) * 64, wc = (w & 1) * 64;
#pragma unroll
    for (int mi = 0; mi < 4; ++mi)
#pragma unroll
        for (int ni = 0; ni < 4; ++ni)
#pragma unroll
            for (int r = 0; r < 4; ++r) {
                int c = cbk * 128 + wr + mi * 16 + (l >> 4) * 4 + r;
                int s = sb * 128 + wc + ni * 16 + (l & 15);
                size_t off = ((size_t)b * C_ + c) * S_ + s;
                out[off] = acc[mi][ni][r] + bo[c] + x[off];
            }
}

// ---------------------------------------------------------------- launch
extern "C" void kernel_launch(void* const* d_in, const int* in_sizes, int n_in,
                              void* d_out, int out_size, void* d_ws, size_t ws_size,
                              hipStream_t stream) {
    const float* x  = (const float*)d_in[0];
    const float* gw = (const float*)d_in[1];
    const float* gb = (const float*)d_in[2];
    const float* wq = (const float*)d_in[3];
    const float* bq = (const float*)d_in[4];
    const float* wk = (const float*)d_in[5];
    const float* bk = (const float*)d_in[6];
    const float* wv = (const float*)d_in[7];
    const float* bv = (const float*)d_in[8];
    const float* wo = (const float*)d_in[9];
    const float* bo = (const float*)d_in[10];
    float* out = (float*)d_out;

    char* ws = (char*)d_ws;
    const size_t SEQ_BYTES = (size_t)BS * C_ * 2;           // 16 MB
    float* part           = (float*)ws;                                        // 4 KB
    unsigned short* seq   = (unsigned short*)(ws + 4096);
    unsigned short* wqkv  = (unsigned short*)(ws + 4096 + SEQ_BYTES);
    unsigned short* wobf  = (unsigned short*)(ws + 4096 + SEQ_BYTES + 1572864);
    unsigned short* qb    = (unsigned short*)(ws + 4096 + SEQ_BYTES + 1572864 + 524288);
    unsigned short* kb    = qb + 8388608;
    unsigned short* vtb   = kb + 8388608;
    unsigned short* attn  = seq;                            // reuse (seq dead after qkv_gemm)

    gn_partial<<<dim3(16, 32), 256, 0, stream>>>(x, part);
    gn_apply_t<<<dim3(16, 8, 16), 256, 0, stream>>>(x, part, gw, gb, seq);
    cvt_w<<<dim3(256, 4), 256, 0, stream>>>(wq, wk, wv, wo, wqkv, wobf);
    qkv_gemm<<<dim3(128, 12), 256, 0, stream>>>(seq, wqkv, bq, bk, bv, qb, kb, vtb);
    flash_attn<<<dim3(64, 8), 256, 0, stream>>>(qb, kb, vtb, attn);
    oproj_gemm<<<dim3(4, 8, 16), 256, 0, stream>>>(wobf, attn, bo, x, out);
}

// Round 14
// 145.648 us; speedup vs baseline: 1.0600x; 1.0600x over previous
//
#include <hip/hip_runtime.h>
#include <stdint.h>

#define B_  16
#define C_  512
#define S_  1024
#define NH  4
#define HD  128
#define BS  (B_*S_)

typedef __attribute__((ext_vector_type(8))) short   short8;
typedef __attribute__((ext_vector_type(4))) float   f32x4;
typedef __attribute__((ext_vector_type(4))) unsigned int uint4v;

__device__ __forceinline__ unsigned short f2bf(float f) {
    unsigned u = __float_as_uint(f);
    unsigned r = (u + 0x7fffu + ((u >> 16) & 1u)) >> 16;
    return (unsigned short)r;
}

__device__ __forceinline__ unsigned cvt_pk_bf16(float a, float b) {
    unsigned r;
    asm("v_cvt_pk_bf16_f32 %0, %1, %2" : "=v"(r) : "v"(a), "v"(b));
    return r;
}

// ---------------------------------------------------------------- GroupNorm
__global__ void gn_partial(const float* __restrict__ x, float* __restrict__ part) {
    int b = blockIdx.x, chunk = blockIdx.y;           // 16 x 32
    const float4* xb = (const float4*)(x + (size_t)b * C_ * S_);
    int base = chunk * 4096 + threadIdx.x;
    float s = 0.f, ss = 0.f;
#pragma unroll
    for (int i = 0; i < 16; ++i) {
        float4 v = xb[base + i * 256];
        s  += v.x + v.y + v.z + v.w;
        ss += v.x*v.x + v.y*v.y + v.z*v.z + v.w*v.w;
    }
    for (int off = 32; off; off >>= 1) { s += __shfl_down(s, off); ss += __shfl_down(ss, off); }
    __shared__ float red[2][4];
    int wv = threadIdx.x >> 6;
    if ((threadIdx.x & 63) == 0) { red[0][wv] = s; red[1][wv] = ss; }
    __syncthreads();
    if (threadIdx.x == 0) {
        s  = red[0][0] + red[0][1] + red[0][2] + red[0][3];
        ss = red[1][0] + red[1][1] + red[1][2] + red[1][3];
        part[(b*32 + chunk)*2 + 0] = s;
        part[(b*32 + chunk)*2 + 1] = ss;
    }
}

// apply GN + transpose (B,C,S) -> (B,S,C) bf16
__global__ void gn_apply_t(const float* __restrict__ x, const float* __restrict__ part,
                           const float* __restrict__ gw, const float* __restrict__ gb,
                           unsigned short* __restrict__ seq) {
    int st = blockIdx.x, ct = blockIdx.y, b = blockIdx.z;   // 16, 8, 16
    float s1 = 0.f, s2 = 0.f;
#pragma unroll
    for (int i = 0; i < 32; ++i) { s1 += part[(b*32+i)*2]; s2 += part[(b*32+i)*2+1]; }
    const float invN = 1.0f / (float)(C_ * S_);
    float mean = s1 * invN;
    float var  = s2 * invN - mean * mean;
    float rstd = rsqrtf(var + 1e-5f);

    __shared__ unsigned short tile[64][72];
    int c0 = ct * 64, s0 = st * 64;
    const float* xb = x + ((size_t)b * C_ + c0) * S_ + s0;
    int tr = threadIdx.x >> 4, tj = (threadIdx.x & 15) * 4;
#pragma unroll
    for (int p = 0; p < 4; ++p) {
        int i = tr + p * 16;
        float w  = gw[c0 + i];
        float bb = gb[c0 + i];
        float4 v = *(const float4*)(xb + (size_t)i * S_ + tj);
        tile[i][tj+0] = f2bf((v.x - mean) * rstd * w + bb);
        tile[i][tj+1] = f2bf((v.y - mean) * rstd * w + bb);
        tile[i][tj+2] = f2bf((v.z - mean) * rstd * w + bb);
        tile[i][tj+3] = f2bf((v.w - mean) * rstd * w + bb);
    }
    __syncthreads();
    int j  = threadIdx.x >> 2;
    int cc = (threadIdx.x & 3) * 16;
    unsigned short tmp[16] __attribute__((aligned(16)));
#pragma unroll
    for (int i = 0; i < 16; ++i) tmp[i] = tile[cc + i][j];
    unsigned short* dst = seq + ((size_t)(b * S_ + s0 + j)) * C_ + c0 + cc;
    *(uint4v*)dst       = *(uint4v*)tmp;
    *(uint4v*)(dst + 8) = *(uint4v*)(tmp + 8);
}

// ---------------------------------------------------------------- weights cast
__global__ void cvt_w(const float* __restrict__ wq, const float* __restrict__ wk,
                      const float* __restrict__ wv, const float* __restrict__ wo,
                      unsigned short* __restrict__ wqkv, unsigned short* __restrict__ wobf) {
    int m = blockIdx.y;
    const float* src = (m == 0) ? wq : (m == 1) ? wk : (m == 2) ? wv : wo;
    unsigned short* dst = (m < 3) ? (wqkv + (size_t)m * C_ * C_) : wobf;
    int i = blockIdx.x * 256 + threadIdx.x;                 // 65536 float4 per matrix
    float4 v = ((const float4*)src)[i];
    unsigned short o[4] __attribute__((aligned(8)));
    o[0] = f2bf(v.x); o[1] = f2bf(v.y); o[2] = f2bf(v.z); o[3] = f2bf(v.w);
    *(unsigned long long*)(dst + (size_t)i * 4) = *(unsigned long long*)o;
}

// ---------------------------------------------------------------- 128x128 GEMM core
// C[m][n] = sum_k A[m][k]*B[n][k]; A,B row-major bf16 with row stride K.
__device__ __forceinline__ void gemm128_bt(const unsigned short* __restrict__ Ab,
                                           const unsigned short* __restrict__ Bb,
                                           const int K,
                                           unsigned short* lA, unsigned short* lB,
                                           f32x4 acc[4][4]) {
    const int t = threadIdx.x;
    const int w = t >> 6, l = t & 63;
    const int wr = (w >> 1) * 64, wc = (w & 1) * 64;
    const int lrow = l & 15;
    const int lk8  = (l >> 4) * 8;
#pragma unroll
    for (int mi = 0; mi < 4; ++mi)
#pragma unroll
        for (int ni = 0; ni < 4; ++ni)
            acc[mi][ni] = (f32x4){0.f, 0.f, 0.f, 0.f};

    for (int kt = 0; kt < K; kt += 64) {
#pragma unroll
        for (int j = 0; j < 4; ++j) {
            const int lin = j * 256 + t;
            const int row = lin >> 3, ch = lin & 7;
            __builtin_amdgcn_global_load_lds(
                (const __attribute__((address_space(1))) unsigned int*)(Ab + (size_t)row * K + kt + ch * 8),
                (__attribute__((address_space(3))) unsigned int*)(lA + (size_t)(j * 256 + w * 64) * 8),
                16, 0, 0);
        }
#pragma unroll
        for (int j = 0; j < 4; ++j) {
            const int lin = j * 256 + t;
            const int row = lin >> 3, ch = lin & 7;
            __builtin_amdgcn_global_load_lds(
                (const __attribute__((address_space(1))) unsigned int*)(Bb + (size_t)row * K + kt + ch * 8),
                (__attribute__((address_space(3))) unsigned int*)(lB + (size_t)(j * 256 + w * 64) * 8),
                16, 0, 0);
        }
        __syncthreads();
#pragma unroll
        for (int kk = 0; kk < 2; ++kk) {
            short8 af[4], bf[4];
            const int ko = lk8 + kk * 32;
#pragma unroll
            for (int mi = 0; mi < 4; ++mi)
                af[mi] = *(const short8*)&lA[(size_t)(wr + mi * 16 + lrow) * 64 + ko];
#pragma unroll
            for (int ni = 0; ni < 4; ++ni)
                bf[ni] = *(const short8*)&lB[(size_t)(wc + ni * 16 + lrow) * 64 + ko];
#pragma unroll
            for (int mi = 0; mi < 4; ++mi)
#pragma unroll
                for (int ni = 0; ni < 4; ++ni)
                    acc[mi][ni] = __builtin_amdgcn_mfma_f32_16x16x32_bf16(af[mi], bf[ni], acc[mi][ni], 0, 0, 0);
        }
        __syncthreads();
    }
}

// ---------------------------------------------------------------- QKV GEMM (+fused V transpose)
// Q/K epilogue: stage (s,d) tile in LDS, then fully-coalesced b128 stores
// (the per-block output region of (b,h,s,d) is one contiguous 32KB range).
__global__ __launch_bounds__(256) void qkv_gemm(
        const unsigned short* __restrict__ seq, const unsigned short* __restrict__ wqkv,
        const float* __restrict__ bq, const float* __restrict__ bk, const float* __restrict__ bv,
        unsigned short* __restrict__ qb, unsigned short* __restrict__ kb, unsigned short* __restrict__ vtb) {
    __shared__ unsigned short sbuf[128 * 136];              // gemm: first 16384; epilogue: all
    unsigned short* lA = sbuf;
    unsigned short* lB = sbuf + 128 * 64;
    int mb = blockIdx.x, nb = blockIdx.y;                   // 128, 12
    f32x4 acc[4][4];
    gemm128_bt(seq + (size_t)mb * 128 * C_, wqkv + (size_t)nb * 128 * C_, C_, lA, lB, acc);

    int mat = nb >> 2;                                      // 0=q 1=k 2=v
    int w = threadIdx.x >> 6, l = threadIdx.x & 63;
    int l15 = l & 15, g = l >> 4;
    int wr = (w >> 1) * 64, wc = (w & 1) * 64;
    int b  = mb >> 3;
    int s0 = (mb & 7) * 128;
    int h  = nb & 3;

    if (mat < 2) {
        const float* bias = (mat == 0) ? bq : bk;
        unsigned short* out = (mat == 0) ? qb : kb;
        // q scale: 1/sqrt(128) * log2(e)  (attention computed in exp2 domain)
        float oscale = (mat == 0) ? 0.12751879523087253f : 1.0f;
#pragma unroll
        for (int mi = 0; mi < 4; ++mi)
#pragma unroll
            for (int ni = 0; ni < 4; ++ni) {
                int dloc = wc + ni * 16 + l15;               // d
                int sloc = wr + mi * 16 + g * 4;             // s (rows sloc..sloc+3)
                float bia = bias[h * 128 + dloc];
#pragma unroll
                for (int r = 0; r < 4; ++r)
                    sbuf[(sloc + r) * 136 + dloc] = f2bf((acc[mi][ni][r] + bia) * oscale);
            }
        __syncthreads();
        unsigned short* dst = out + ((size_t)(b * NH + h) * S_ + s0) * HD;
#pragma unroll
        for (int p = 0; p < 4; ++p) {
            int idx = p * 256 + threadIdx.x;                 // 1024 chunks of 16B
            int srow = idx >> 3, cc = (idx & 7) * 8;
            short8 vv = *(const short8*)&sbuf[srow * 136 + cc];
            *(short8*)(dst + (size_t)idx * 8) = vv;
        }
    } else {
        // V: bias, then transpose through LDS -> vt (b,h,d,s)
#pragma unroll
        for (int mi = 0; mi < 4; ++mi)
#pragma unroll
            for (int ni = 0; ni < 4; ++ni) {
                int dloc = wc + ni * 16 + l15;
                int mloc = wr + mi * 16 + g * 4;
                float bia = bv[h * 128 + dloc];
#pragma unroll
                for (int r = 0; r < 4; ++r)
                    sbuf[dloc * 136 + mloc + r] = f2bf(acc[mi][ni][r] + bia);
            }
        __syncthreads();
        unsigned short* dst = vtb + ((size_t)(b * NH + h)) * HD * S_ + s0;
#pragma unroll
        for (int p = 0; p < 8; ++p) {
            int idx = p * 256 + threadIdx.x;
            int d = idx >> 4, cc = (idx & 15) * 8;
            short8 vv = *(const short8*)&sbuf[d * 136 + cc];
            *(short8*)(dst + (size_t)d * S_ + cc) = vv;
        }
    }
}

// ---------------------------------------------------------------- flash attention
// q,k: (bh, s, d) bf16 (q pre-scaled by 1/sqrt(d)*log2e); vt: (bh, d, s) bf16; o: (b, s, c) bf16
// Swapped QK^T: s = mfma(K, Q) = S^T; lane (g,l15) column q=l15 (half a) / q=l15+16 (half b).
// 4 waves x 32 q-rows = 128 q-rows per block; KVBLK=64; K/V double-buffered with
// issue-early prefetch (one barrier per tile).
__global__ __launch_bounds__(256) void flash_attn(
        const unsigned short* __restrict__ q, const unsigned short* __restrict__ k,
        const unsigned short* __restrict__ vt, unsigned short* __restrict__ o) {
    int bh = blockIdx.x, qblk = blockIdx.y;                 // 64, 8
    int t = threadIdx.x, w = t >> 6, l = t & 63;
    int l15 = l & 15, g = l >> 4;
    int swz = (l15 & 7) << 1;                               // even XOR mask on 8B chunks
    __shared__ unsigned short lK[2][64 * 128];              // [kv][d], swizzled 16B chunks
    __shared__ unsigned short lV[2][128 * 64];              // [d][kv], swizzled 16B chunks
    __shared__ unsigned short lP[4][32 * 64];               // per-wave P [32 q][64 kv], 8B chunks

    const size_t bh_base = (size_t)bh * S_ * HD;
    int q0 = qblk * 128 + w * 32;

    // Q fragments (B operand) for both q-halves
    short8 qa[4], qb_[4];
    const unsigned short* qp = q + bh_base + (size_t)(q0 + l15) * HD + g * 8;
#pragma unroll
    for (int kc = 0; kc < 4; ++kc) {
        qa[kc]  = *(const short8*)(qp + kc * 32);
        qb_[kc] = *(const short8*)(qp + 16 * HD + kc * 32);
    }

    f32x4 oa[8], ob[8];
#pragma unroll
    for (int i = 0; i < 8; ++i) { oa[i] = (f32x4){0.f,0.f,0.f,0.f}; ob[i] = (f32x4){0.f,0.f,0.f,0.f}; }
    float m_a = -1e30f, l_a = 0.f, m_b = -1e30f, l_b = 0.f;
    unsigned short* myP = &lP[w][0];

#define STAGE_TILE(buf, kv0_) do {                                                     \
    int kv0s = (kv0_);                                                                 \
    _Pragma("unroll")                                                                  \
    for (int j = 0; j < 4; ++j) {                                                      \
        int lin = j * 256 + t;                                                         \
        int row = lin >> 4, c16 = lin & 15;                                            \
        int sc  = (c16 & 8) | ((c16 ^ row) & 7);                                       \
        __builtin_amdgcn_global_load_lds(                                              \
            (const __attribute__((address_space(1))) unsigned int*)(k + bh_base + (size_t)(kv0s + row) * HD + sc * 8), \
            (__attribute__((address_space(3))) unsigned int*)(&lK[buf][0] + (size_t)(j * 256 + w * 64) * 8), \
            16, 0, 0);                                                                 \
    }                                                                                  \
    _Pragma("unroll")                                                                  \
    for (int j = 0; j < 4; ++j) {                                                      \
        int lin = j * 256 + t;                                                         \
        int row = lin >> 3, c8 = lin & 7;                                              \
        int sc  = (c8 ^ row) & 7;                                                      \
        __builtin_amdgcn_global_load_lds(                                              \
            (const __attribute__((address_space(1))) unsigned int*)(vt + bh_base + (size_t)row * S_ + kv0s + sc * 8), \
            (__attribute__((address_space(3))) unsigned int*)(&lV[buf][0] + (size_t)(j * 256 + w * 64) * 8), \
            16, 0, 0);                                                                 \
    }                                                                                  \
} while (0)

    STAGE_TILE(0, 0);
    __syncthreads();
    int cur = 0;

    for (int kt = 0; kt < 16; ++kt) {
        if (kt < 15) STAGE_TILE(cur ^ 1, (kt + 1) * 64);    // prefetch overlaps compute
        const unsigned short* lKc = &lK[cur][0];
        const unsigned short* lVc = &lV[cur][0];

        // S^T = K @ Q^T for both q-halves (K frag read once, used twice)
        f32x4 sa[4], sb[4];
#pragma unroll
        for (int nb = 0; nb < 4; ++nb) {
            sa[nb] = (f32x4){0.f,0.f,0.f,0.f};
            sb[nb] = (f32x4){0.f,0.f,0.f,0.f};
        }
#pragma unroll
        for (int kc = 0; kc < 4; ++kc)
#pragma unroll
            for (int nb = 0; nb < 4; ++nb) {
                int row = nb * 16 + l15;
                int gg  = g + kc * 4;
                int ch  = (gg & 8) | ((gg ^ row) & 7);
                short8 kf = *(const short8*)&lKc[(size_t)row * 128 + ch * 8];
                sa[nb] = __builtin_amdgcn_mfma_f32_16x16x32_bf16(kf, qa[kc],  sa[nb], 0, 0, 0);
                sb[nb] = __builtin_amdgcn_mfma_f32_16x16x32_bf16(kf, qb_[kc], sb[nb], 0, 0, 0);
            }

        // row max per half (q = l15 / l15+16)
        float mxa = fmaxf(fmaxf(sa[0][0], sa[0][1]), fmaxf(sa[0][2], sa[0][3]));
        float mxb = fmaxf(fmaxf(sb[0][0], sb[0][1]), fmaxf(sb[0][2], sb[0][3]));
#pragma unroll
        for (int nb = 1; nb < 4; ++nb) {
            mxa = fmaxf(mxa, fmaxf(fmaxf(sa[nb][0], sa[nb][1]), fmaxf(sa[nb][2], sa[nb][3])));
            mxb = fmaxf(mxb, fmaxf(fmaxf(sb[nb][0], sb[nb][1]), fmaxf(sb[nb][2], sb[nb][3])));
        }
        mxa = fmaxf(mxa, __shfl_xor(mxa, 16)); mxa = fmaxf(mxa, __shfl_xor(mxa, 32));
        mxb = fmaxf(mxb, __shfl_xor(mxb, 16)); mxb = fmaxf(mxb, __shfl_xor(mxb, 32));

        // defer-max: rescale only when a row grew by > 8 (log2 units)
        if (!__all((mxa - m_a <= 8.f) && (mxb - m_b <= 8.f))) {
            float mna = fmaxf(m_a, mxa), mnb = fmaxf(m_b, mxb);
            float ala = exp2f(m_a - mna), alb = exp2f(m_b - mnb);
            m_a = mna; m_b = mnb; l_a *= ala; l_b *= alb;
            float a0 = __shfl(ala, g*4+0), a1 = __shfl(ala, g*4+1),
                  a2 = __shfl(ala, g*4+2), a3 = __shfl(ala, g*4+3);
            float b0 = __shfl(alb, g*4+0), b1 = __shfl(alb, g*4+1),
                  b2 = __shfl(alb, g*4+2), b3 = __shfl(alb, g*4+3);
#pragma unroll
            for (int dn = 0; dn < 8; ++dn) {
                oa[dn][0] *= a0; oa[dn][1] *= a1; oa[dn][2] *= a2; oa[dn][3] *= a3;
                ob[dn][0] *= b0; ob[dn][1] *= b1; ob[dn][2] *= b2; ob[dn][3] *= b3;
            }
        }

        // P = exp2(S - m); pack 4 kv -> one b64 store per (nb, half)
        float psa = 0.f, psb = 0.f;
#pragma unroll
        for (int nb = 0; nb < 4; ++nb) {
            float p0 = exp2f(sa[nb][0] - m_a), p1 = exp2f(sa[nb][1] - m_a);
            float p2 = exp2f(sa[nb][2] - m_a), p3 = exp2f(sa[nb][3] - m_a);
            psa += (p0 + p1) + (p2 + p3);
            unsigned d0 = cvt_pk_bf16(p0, p1), d1 = cvt_pk_bf16(p2, p3);
            int c = (nb * 4 + g) ^ swz;
            *(unsigned long long*)(myP + l15 * 64 + c * 4) =
                (unsigned long long)d0 | ((unsigned long long)d1 << 32);
            float r0 = exp2f(sb[nb][0] - m_b), r1 = exp2f(sb[nb][1] - m_b);
            float r2 = exp2f(sb[nb][2] - m_b), r3 = exp2f(sb[nb][3] - m_b);
            psb += (r0 + r1) + (r2 + r3);
            unsigned e0 = cvt_pk_bf16(r0, r1), e1 = cvt_pk_bf16(r2, r3);
            *(unsigned long long*)(myP + (l15 + 16) * 64 + c * 4) =
                (unsigned long long)e0 | ((unsigned long long)e1 << 32);
        }
        psa += __shfl_xor(psa, 16); psa += __shfl_xor(psa, 32);
        psb += __shfl_xor(psb, 16); psb += __shfl_xor(psb, 32);
        l_a += psa; l_b += psb;

        // O += P @ V  (V frag read once, used for both halves)
#pragma unroll
        for (int kc = 0; kc < 2; ++kc) {
            int c0 = (kc * 8 + g * 2) ^ swz;                // even; pair (c0,c0+1) = one b128
            short8 pa = *(const short8*)(myP + l15 * 64 + c0 * 4);
            short8 pb = *(const short8*)(myP + (l15 + 16) * 64 + c0 * 4);
            int pg = g + kc * 4;
#pragma unroll
            for (int dn = 0; dn < 8; ++dn) {
                int vrow = dn * 16 + l15;
                int vch  = (pg ^ vrow) & 7;
                short8 vf = *(const short8*)&lVc[(size_t)vrow * 64 + vch * 8];
                oa[dn] = __builtin_amdgcn_mfma_f32_16x16x32_bf16(pa, vf, oa[dn], 0, 0, 0);
                ob[dn] = __builtin_amdgcn_mfma_f32_16x16x32_bf16(pb, vf, ob[dn], 0, 0, 0);
            }
        }
        __syncthreads();                                    // prefetch landed; buffers swappable
        cur ^= 1;
    }
#undef STAGE_TILE

    float ia = 1.0f / l_a, ib = 1.0f / l_b;
    float ia0 = __shfl(ia, g*4+0), ia1 = __shfl(ia, g*4+1),
          ia2 = __shfl(ia, g*4+2), ia3 = __shfl(ia, g*4+3);
    float ib0 = __shfl(ib, g*4+0), ib1 = __shfl(ib, g*4+1),
          ib2 = __shfl(ib, g*4+2), ib3 = __shfl(ib, g*4+3);
    int b = bh >> 2, h = bh & 3;
    int sra = q0 + g * 4;
#pragma unroll
    for (int dn = 0; dn < 8; ++dn) {
        int cbase = h * HD + dn * 16 + l15;
        o[((size_t)(b * S_ + sra + 0)) * C_ + cbase]  = f2bf(oa[dn][0] * ia0);
        o[((size_t)(b * S_ + sra + 1)) * C_ + cbase]  = f2bf(oa[dn][1] * ia1);
        o[((size_t)(b * S_ + sra + 2)) * C_ + cbase]  = f2bf(oa[dn][2] * ia2);
        o[((size_t)(b * S_ + sra + 3)) * C_ + cbase]  = f2bf(oa[dn][3] * ia3);
        o[((size_t)(b * S_ + sra + 16)) * C_ + cbase] = f2bf(ob[dn][0] * ib0);
        o[((size_t)(b * S_ + sra + 17)) * C_ + cbase] = f2bf(ob[dn][1] * ib1);
        o[((size_t)(b * S_ + sra + 18)) * C_ + cbase] = f2bf(ob[dn][2] * ib2);
        o[((size_t)(b * S_ + sra + 19)) * C_ + cbase] = f2bf(ob[dn][3] * ib3);
    }
}

// ---------------------------------------------------------------- out-proj (+bias+residual)
// computes out[b][c][s] = sum_k wo[c][k]*attn[b][s][k] + bo[c] + x[b][c][s]
__global__ __launch_bounds__(256) void oproj_gemm(
        const unsigned short* __restrict__ wobf, const unsigned short* __restrict__ attn,
        const float* __restrict__ bo, const float* __restrict__ x, float* __restrict__ out) {
    int cbk = blockIdx.x, sb = blockIdx.y, b = blockIdx.z;  // 4, 8, 16
    __shared__ unsigned short lA[128 * 64], lB[128 * 64];
    f32x4 acc[4][4];
    gemm128_bt(wobf + (size_t)cbk * 128 * C_,
               attn + ((size_t)b * S_ + sb * 128) * C_, C_, lA, lB, acc);

    int w = threadIdx.x >> 6, l = threadIdx.x & 63;
    int wr = (w >> 1) * 64, wc = (w & 1) * 64;
#pragma unroll
    for (int mi = 0; mi < 4; ++mi)
#pragma unroll
        for (int ni = 0; ni < 4; ++ni)
#pragma unroll
            for (int r = 0; r < 4; ++r) {
                int c = cbk * 128 + wr + mi * 16 + (l >> 4) * 4 + r;
                int s = sb * 128 + wc + ni * 16 + (l & 15);
                size_t off = ((size_t)b * C_ + c) * S_ + s;
                out[off] = acc[mi][ni][r] + bo[c] + x[off];
            }
}

// ---------------------------------------------------------------- launch
extern "C" void kernel_launch(void* const* d_in, const int* in_sizes, int n_in,
                              void* d_out, int out_size, void* d_ws, size_t ws_size,
                              hipStream_t stream) {
    const float* x  = (const float*)d_in[0];
    const float* gw = (const float*)d_in[1];
    const float* gb = (const float*)d_in[2];
    const float* wq = (const float*)d_in[3];
    const float* bq = (const float*)d_in[4];
    const float* wk = (const float*)d_in[5];
    const float* bk = (const float*)d_in[6];
    const float* wv = (const float*)d_in[7];
    const float* bv = (const float*)d_in[8];
    const float* wo = (const float*)d_in[9];
    const float* bo = (const float*)d_in[10];
    float* out = (float*)d_out;

    char* ws = (char*)d_ws;
    const size_t SEQ_BYTES = (size_t)BS * C_ * 2;           // 16 MB
    float* part           = (float*)ws;                                        // 4 KB
    unsigned short* seq   = (unsigned short*)(ws + 4096);
    unsigned short* wqkv  = (unsigned short*)(ws + 4096 + SEQ_BYTES);
    unsigned short* wobf  = (unsigned short*)(ws + 4096 + SEQ_BYTES + 1572864);
    unsigned short* qb    = (unsigned short*)(ws + 4096 + SEQ_BYTES + 1572864 + 524288);
    unsigned short* kb    = qb + 8388608;
    unsigned short* vtb   = kb + 8388608;
    unsigned short* attn  = seq;                            // reuse (seq dead after qkv_gemm)

    gn_partial<<<dim3(16, 32), 256, 0, stream>>>(x, part);
    gn_apply_t<<<dim3(16, 8, 16), 256, 0, stream>>>(x, part, gw, gb, seq);
    cvt_w<<<dim3(256, 4), 256, 0, stream>>>(wq, wk, wv, wo, wqkv, wobf);
    qkv_gemm<<<dim3(128, 12), 256, 0, stream>>>(seq, wqkv, bq, bk, bv, qb, kb, vtb);
    flash_attn<<<dim3(64, 8), 256, 0, stream>>>(qb, kb, vtb, attn);
    oproj_gemm<<<dim3(4, 8, 16), 256, 0, stream>>>(wobf, attn, bo, x, out);
}